// Round 3
// baseline (330.765 us; speedup 1.0000x reference)
//
#include <hip/hip_runtime.h>
#include <hip/hip_cooperative_groups.h>
#include <stdint.h>

namespace cg = cooperative_groups;

#define NANCH 17064
#define NQUAD 4266
#define BATCH 16
#define NCLS 80
#define KDET 1000
#define SCORE_THR 0.05f
#define IOU_THR 0.6f

typedef unsigned long long u64;
typedef unsigned int u32;

__device__ __forceinline__ float sigf(float x) { return 1.0f / (1.0f + expf(-x)); }

__device__ __forceinline__ void decode_anchor(int n, int& l, int& h, int& w) {
  if (n < 12800)      { l = 0; h = n >> 7;               w = n & 127; }
  else if (n < 16000) { l = 1; int r = n - 12800; h = r >> 6; w = r & 63; }
  else if (n < 16800) { l = 2; int r = n - 16000; h = r >> 5; w = r & 31; }
  else if (n < 17008) { l = 3; int r = n - 16800; h = r >> 4; w = r & 15; }
  else                { l = 4; int r = n - 17008; h = r >> 3; w = r & 7; }
}

// encode float for monotone u32 atomicMax
__device__ __forceinline__ u32 fenc(float f) {
  u32 u = __float_as_uint(f);
  return (u & 0x80000000u) ? ~u : (u | 0x80000000u);
}
__device__ __forceinline__ float fdec(u32 e) {
  u32 u = (e & 0x80000000u) ? (e ^ 0x80000000u) : ~e;
  return __uint_as_float(u);
}

struct Params {
  const float* cls0; const float* ctr0; const float* reg0;
  const float* cls1; const float* ctr1; const float* reg1;
  const float* cls2; const float* ctr2; const float* reg2;
  const float* cls3; const float* ctr3; const float* reg3;
  const float* cls4; const float* ctr4; const float* reg4;
  u32* sb; u32* cl8; u64* candG; int* cntG; u32* maxcG;
  float* scoreG; int* clsG; float4* boxG; u64* mat; float* out;
};

// ============================================================================
// Single cooperative megakernel: 128 blocks x 1024 threads, co-resident
// (VGPR<=128 via launch_bounds -> 16 waves/CU -> 1 block/CU, 128 <= 256 CUs).
// Phases separated by grid.sync(); each phase keeps its natural parallelism.
// Eliminates 4 kernel launch/drain gaps that dominated the 5-kernel pipeline.
// ============================================================================
__global__ __launch_bounds__(1024, 4) void k_mega(Params p)
{
  __shared__ __align__(16) char smem[32896];
  __shared__ int sh_T1, sh_ab, sh_T2, sh_cnt, sh_chg;

  cg::grid_group grid = cg::this_grid();
  const int tid = threadIdx.x;
  const int blk = blockIdx.x;          // 0..127
  const int lane = tid & 63;
  const int wv = tid >> 6;             // 0..15

  // ================= phase 1: per-anchor scores =================
  // 1072 virtual (64,4)-blocks, 4 sub-blocks per real block, 3 passes.
  {
    const int g = tid >> 8;            // sub-block 0..3
    const int x = tid & 63;
    const int y = (tid >> 6) & 3;
    float* smF = (float*)smem;                 // [g][y][x] stride 5
    u32*   saP = (u32*)(smem + 20480);         // [g][y][x]
    for (int pass = 0; pass < 3; ++pass) {
      int vb = pass * 512 + blk * 4 + g;       // 0..1535
      int vbc = vb < 1072 ? vb : 1071;
      int b  = vbc / 67;
      int bx = vbc - b * 67;
      int q  = bx * 64 + x;
      bool act = (vb < 1072) && (q < NQUAD);
      int qc = q < NQUAD ? q : (NQUAD - 1);
      int n = qc * 4;

      const float* cp; const float* tp; int hw, off;
      if (n < 12800)      { cp = p.cls0; tp = p.ctr0; hw = 12800; off = n; }
      else if (n < 16000) { cp = p.cls1; tp = p.ctr1; hw = 3200;  off = n - 12800; }
      else if (n < 16800) { cp = p.cls2; tp = p.ctr2; hw = 800;   off = n - 16000; }
      else if (n < 17008) { cp = p.cls3; tp = p.ctr3; hw = 208;   off = n - 16800; }
      else                { cp = p.cls4; tp = p.ctr4; hw = 56;    off = n - 17008; }
      const float4* base = (const float4*)(cp + (size_t)b * NCLS * hw + off);
      const int s4 = hw >> 2;
      const int cb = y * 20;

      float4 v[20];
#pragma unroll
      for (int cc = 0; cc < 20; ++cc) v[cc] = base[(size_t)(cb + cc) * s4];

      float m0 = -1.0f, m1 = -1.0f, m2 = -1.0f, m3 = -1.0f;
      int a0 = 0, a1 = 0, a2 = 0, a3 = 0;
#pragma unroll
      for (int cc = 0; cc < 20; ++cc) {
        int c = cb + cc;
        float s;
        s = sigf(v[cc].x); if (s > m0) { m0 = s; a0 = c; }
        s = sigf(v[cc].y); if (s > m1) { m1 = s; a1 = c; }
        s = sigf(v[cc].z); if (s > m2) { m2 = s; a2 = c; }
        s = sigf(v[cc].w); if (s > m3) { m3 = s; a3 = c; }
      }
      int si = ((g * 4 + y) * 64 + x);
      smF[si * 5 + 0] = m0; smF[si * 5 + 1] = m1;
      smF[si * 5 + 2] = m2; smF[si * 5 + 3] = m3;
      saP[si] = (u32)a0 | ((u32)a1 << 8) | ((u32)a2 << 16) | ((u32)a3 << 24);
      __syncthreads();

      if (y == 0 && act) {
#pragma unroll
        for (int k = 1; k < 4; ++k) {
          int sk = ((g * 4 + k) * 64 + x);
          u32 pk = saP[sk];
          float t;
          t = smF[sk * 5 + 0]; if (t > m0) { m0 = t; a0 = (int)(pk & 0xffu); }
          t = smF[sk * 5 + 1]; if (t > m1) { m1 = t; a1 = (int)((pk >> 8) & 0xffu); }
          t = smF[sk * 5 + 2]; if (t > m2) { m2 = t; a2 = (int)((pk >> 16) & 0xffu); }
          t = smF[sk * 5 + 3]; if (t > m3) { m3 = t; a3 = (int)((pk >> 24) & 0xffu); }
        }
        float4 ctv = *(const float4*)(tp + (size_t)b * hw + off);
        uint4 sv;
        sv.x = __float_as_uint(m0 * sigf(ctv.x));
        sv.y = __float_as_uint(m1 * sigf(ctv.y));
        sv.z = __float_as_uint(m2 * sigf(ctv.z));
        sv.w = __float_as_uint(m3 * sigf(ctv.w));
        *(uint4*)(p.sb + b * NANCH + n) = sv;
        p.cl8[(b * NANCH + n) >> 2] = (u32)a0 | ((u32)a1 << 8) | ((u32)a2 << 16) | ((u32)a3 << 24);
      }
      __syncthreads();   // sm/sa reused next pass
    }
  }
  grid.sync();

  // ================= phase 2: radix thresholds + compaction (blocks 0..15) =================
  if (blk < BATCH) {
    const int b = blk;
    u32* subhist = (u32*)smem;                 // 1024 bins x 8 copies
    u32* wtot = (u32*)(smem + 32768);
    const int cpy = tid & 7;
    const u32* sbb = p.sb + b * NANCH;

    u32 sc[17];
#pragma unroll
    for (int k = 0; k < 17; ++k) {
      int n = tid + (k << 10);
      sc[k] = (n < NANCH) ? sbb[n] : 0u;
    }

#pragma unroll
    for (int k = 0; k < 8; ++k) subhist[tid + (k << 10)] = 0;
    __syncthreads();
#pragma unroll
    for (int k = 0; k < 17; ++k) {
      int n = tid + (k << 10);
      if (n < NANCH) atomicAdd(&subhist[((sc[k] >> 22) << 3) + cpy], 1u);
    }
    __syncthreads();
    u32 h = 0;
#pragma unroll
    for (int c2 = 0; c2 < 8; ++c2) h += subhist[(tid << 3) + c2];
    __syncthreads();                    // merge reads done before re-zero
#pragma unroll
    for (int k = 0; k < 8; ++k) subhist[tid + (k << 10)] = 0;
    u32 s = h;
    for (int d = 1; d < 64; d <<= 1) { u32 y2 = (u32)__shfl_down((int)s, d); if (lane + d < 64) s += y2; }
    if (lane == 0) wtot[wv] = s;
    __syncthreads();
    {
      u32 add = 0;
      for (int w2 = wv + 1; w2 < 16; ++w2) add += wtot[w2];
      s += add;
    }
    if (s >= (u32)KDET && s - h < (u32)KDET) { sh_T1 = tid; sh_ab = (int)(s - h); }
    __syncthreads();
    const int T1 = sh_T1; const int above = sh_ab;

#pragma unroll
    for (int k = 0; k < 17; ++k) {
      int n = tid + (k << 10);
      u32 bits = sc[k];
      if (n < NANCH && (int)(bits >> 22) == T1)
        atomicAdd(&subhist[(((bits >> 12) & 1023u) << 3) + cpy], 1u);
    }
    __syncthreads();
    h = 0;
#pragma unroll
    for (int c2 = 0; c2 < 8; ++c2) h += subhist[(tid << 3) + c2];
    s = h;
    for (int d = 1; d < 64; d <<= 1) { u32 y2 = (u32)__shfl_down((int)s, d); if (lane + d < 64) s += y2; }
    if (lane == 0) wtot[wv] = s;
    __syncthreads();
    {
      u32 add = 0;
      for (int w2 = wv + 1; w2 < 16; ++w2) add += wtot[w2];
      s += add;
    }
    if (above + (int)s >= KDET && above + (int)(s - h) < KDET) sh_T2 = tid;
    if (tid == 0) sh_cnt = 0;
    __syncthreads();
    const int T2 = sh_T2;

#pragma unroll
    for (int k = 0; k < 17; ++k) {
      int n = tid + (k << 10);
      u32 bits = sc[k];
      int c1 = (int)(bits >> 22);
      bool cand = (n < NANCH) &&
                  ((c1 > T1) || (c1 == T1 && (int)((bits >> 12) & 1023u) >= T2));
      if (cand) {
        int pos = atomicAdd(&sh_cnt, 1);
        if (pos < 2048) p.candG[b * 2048 + pos] = ((u64)bits << 32) | (u64)(u32)(~(u32)n);
      }
    }
    __syncthreads();
    if (tid == 0) {
      int C = sh_cnt; if (C > 2048) C = 2048;
      p.cntG[b] = C;
      p.maxcG[b] = 0u;
    }
  }
  grid.sync();

  // ================= phase 3: rank (all 128 blocks = 16 batches x 8 chunks) =================
  // Compare loop additionally split 4-way across the 1024 threads (g = tid>>8),
  // partial counts reduced via LDS -> 4x less wall time than 256-thread version.
  {
    const int b = blk >> 3;
    const int c = blk & 7;
    ulonglong2* keys2 = (ulonglong2*)smem;     // 2048 keys
    u32* cntS = (u32*)(smem + 16384);          // 256 counters
    const int C = p.cntG[b];
    const u64* cand = p.candG + b * 2048;

    {
      int i0 = 2 * tid, i1 = 2 * tid + 1;
      ulonglong2 vv;
      vv.x = (i0 < C) ? cand[i0] : 0ull;
      vv.y = (i1 < C) ? cand[i1] : 0ull;
      keys2[tid] = vv;
    }
    if (tid < 256) cntS[tid] = 0;
    __syncthreads();

    const int lidx = tid & 255;
    const int g = tid >> 8;
    const int idx = c * 256 + lidx;
    const bool active = (idx < C);
    u64 key = active ? cand[idx] : 0ull;

    int I = (C + 7) >> 3;        // 8-key steps
    int Iq = (I + 3) >> 2;
    int it0 = g * Iq;
    int it1 = I < it0 + Iq ? I : it0 + Iq;
    int cnt = 0;
    for (int it = it0; it < it1; ++it) {
      int s = it * 4;
      ulonglong2 a0 = keys2[s], a1 = keys2[s + 1], a2 = keys2[s + 2], a3 = keys2[s + 3];
      cnt += (a0.x > key) + (a0.y > key) + (a1.x > key) + (a1.y > key)
           + (a2.x > key) + (a2.y > key) + (a3.x > key) + (a3.y > key);
    }
    atomicAdd(&cntS[lidx], (u32)cnt);
    __syncthreads();

    if (g == 0) {
      int cf = (int)cntS[lidx];
      u32 enc = 0u;
      if (active && cf < KDET) {
        u32 bits = (u32)(key >> 32);
        int n = (int)(~(u32)(key & 0xFFFFFFFFull));
        float score = __uint_as_float(bits);
        int clsv = (int)((const unsigned char*)p.cl8)[b * NANCH + n] + 1;
        int l, hh, ww; decode_anchor(n, l, hh, ww);
        const float* rp; int W, ST, HF, hw;
        switch (l) {
          case 0: rp = p.reg0; W = 128; ST = 8;   HF = 4;  hw = 12800; break;
          case 1: rp = p.reg1; W = 64;  ST = 16;  HF = 8;  hw = 3200;  break;
          case 2: rp = p.reg2; W = 32;  ST = 32;  HF = 16; hw = 800;   break;
          case 3: rp = p.reg3; W = 16;  ST = 64;  HF = 32; hw = 208;   break;
          default: rp = p.reg4; W = 8;  ST = 128; HF = 64; hw = 56;    break;
        }
        float cx = (float)(ww * ST + HF);
        float cy = (float)(hh * ST + HF);
        const float* rb = rp + (size_t)b * 4 * hw + hh * W + ww;
        float r0 = rb[0], r1 = rb[hw], r2 = rb[2 * hw], r3 = rb[3 * hw];
        float4 bx = make_float4(cx - r0, cy - r1, cx + r2, cy + r3);
        int o = b * KDET + cf;
        p.scoreG[o] = score; p.clsG[o] = clsv; p.boxG[o] = bx;
        enc = fenc(fmaxf(fmaxf(bx.x, bx.y), fmaxf(bx.z, bx.w)));
      }
      for (int d = 32; d > 0; d >>= 1) {
        u32 o = (u32)__shfl_xor((int)enc, d);
        enc = (o > enc) ? o : enc;
      }
      if ((tid & 63) == 0 && enc != 0u) atomicMax(p.maxcG + b, enc);
    }
  }
  grid.sync();

  // ================= phase 4: suppression matrix (grid-stride tile-waves) =================
  {
    for (int t = blk * 16 + wv; t < 136 * BATCH; t += 128 * 16) {
      int b = t / 136;
      int tile = t - b * 136;
      int rt = 0, rem = tile;
      while (rem >= rt + 1) { rem -= rt + 1; ++rt; }
      const int wc = rem;

      const float scale = fdec(p.maxcG[b]) + 1.0f;

      const int j = (wc << 6) + lane;
      float jx1 = 0, jy1 = 0, jx2 = 0, jy2 = 0, aj = 0;
      if (j < KDET) {
        float4 bj = p.boxG[b * KDET + j];
        float off = (float)p.clsG[b * KDET + j] * scale;
        jx1 = bj.x + off; jy1 = bj.y + off; jx2 = bj.z + off; jy2 = bj.w + off;
        aj = (jx2 - jx1 + 1.0f) * (jy2 - jy1 + 1.0f);
      }
      const int ri = (rt << 6) + lane;
      float ix1 = 0, iy1 = 0, ix2 = 0, iy2 = 0;
      if (ri < KDET) {
        float4 bi = p.boxG[b * KDET + ri];
        float off = (float)p.clsG[b * KDET + ri] * scale;
        ix1 = bi.x + off; iy1 = bi.y + off; ix2 = bi.z + off; iy2 = bi.w + off;
      }

      u64 myword = 0ull;
      for (int r = 0; r < 64; ++r) {
        float x1 = __shfl(ix1, r), y1 = __shfl(iy1, r);
        float x2 = __shfl(ix2, r), y2 = __shfl(iy2, r);
        float ai = (x2 - x1 + 1.0f) * (y2 - y1 + 1.0f);
        int row = (rt << 6) + r;
        float xmin = fmaxf(x1, jx1), ymin = fmaxf(y1, jy1);
        float xmax = fminf(x2, jx2), ymax = fminf(y2, jy2);
        float inter = fmaxf(xmax - xmin, 0.0f) * fmaxf(ymax - ymin, 0.0f);
        float iou = inter / ((ai + aj) - inter);
        bool pr = (j < row) && (j < KDET) && (iou > IOU_THR);
        u64 mm = __ballot(pr);
        if (lane == r) myword = mm;
      }
      const int rowl = (rt << 6) + lane;
      if (rowl < KDET) p.mat[(size_t)b * (KDET * 16) + rowl * 16 + wc] = myword;
    }
  }
  grid.sync();

  // ================= phase 5: Jacobi-fixpoint NMS + outputs (blocks 0..15) =================
  if (blk < BATCH) {
    const int b = blk;
    u64* keptS = (u64*)smem;

    float sc = (tid < KDET) ? p.scoreG[b * KDET + tid] : 0.0f;
    bool valid = (tid < KDET) && (sc >= SCORE_THR);

    u64 row[16];
    const u64* mrow = p.mat + (size_t)b * (KDET * 16) + (size_t)tid * 16;
    const int wtop = tid >> 6;
#pragma unroll
    for (int w = 0; w < 16; ++w)
      row[w] = (tid < KDET && w <= wtop) ? mrow[w] : 0ull;

    {
      u64 mb = __ballot(valid);
      if (lane == 0) keptS[wv] = mb;
    }
    __syncthreads();

    for (int it = 0; it < KDET + 1; ++it) {
      u64 sup = 0;
#pragma unroll
      for (int w = 0; w < 16; ++w)
        if (w <= wtop) sup |= keptS[w] & row[w];
      bool nk = valid && (sup == 0ull);
      u64 nw = __ballot(nk);
      if (tid == 0) sh_chg = 0;
      __syncthreads();
      if (lane == 0) {
        if (nw != keptS[wv]) sh_chg = 1;
        keptS[wv] = nw;
      }
      __syncthreads();
      if (sh_chg == 0) break;
    }

    if (tid < KDET) {
      bool kp = ((keptS[tid >> 6] >> (tid & 63)) & 1ull) != 0ull;
      int o1 = b * KDET + tid;
      p.out[o1] = kp ? sc : 0.0f;
      p.out[BATCH * KDET + o1] = kp ? (float)p.clsG[o1] : 0.0f;
      float4 bx = p.boxG[o1];
      float* ob = p.out + 2 * BATCH * KDET + (size_t)o1 * 4;
      ob[0] = kp ? bx.x : 0.0f;
      ob[1] = kp ? bx.y : 0.0f;
      ob[2] = kp ? bx.z : 0.0f;
      ob[3] = kp ? bx.w : 0.0f;
    }
  }
}

extern "C" void kernel_launch(void* const* d_in, const int* in_sizes, int n_in,
                              void* d_out, int out_size, void* d_ws, size_t ws_size,
                              hipStream_t stream) {
  char* ws = (char*)d_ws;
  Params p;
  p.cls0 = (const float*)d_in[0];  p.ctr0 = (const float*)d_in[1];  p.reg0 = (const float*)d_in[2];
  p.cls1 = (const float*)d_in[3];  p.ctr1 = (const float*)d_in[4];  p.reg1 = (const float*)d_in[5];
  p.cls2 = (const float*)d_in[6];  p.ctr2 = (const float*)d_in[7];  p.reg2 = (const float*)d_in[8];
  p.cls3 = (const float*)d_in[9];  p.ctr3 = (const float*)d_in[10]; p.reg3 = (const float*)d_in[11];
  p.cls4 = (const float*)d_in[12]; p.ctr4 = (const float*)d_in[13]; p.reg4 = (const float*)d_in[14];
  // mat region (0 .. 2,048,000) is overlaid by sb/cl8/candG, all dead before phase 4 writes.
  p.sb    = (u32*)ws;                       // 1,092,096 B (dead after phase 2)
  p.cl8   = (u32*)(ws + 1092096);           //   273,024 B (dead after phase 3)
  p.candG = (u64*)(ws + 1365120);           //   262,144 B (dead after phase 3)
  p.mat   = (u64*)ws;                       // 2,048,000 B (phase 4 -> 5)
  p.scoreG = (float*) (ws + 2048000);       //    64,000 B
  p.clsG   = (int*)   (ws + 2112000);       //    64,000 B
  p.boxG   = (float4*)(ws + 2176000);       //   256,000 B
  p.cntG   = (int*)   (ws + 2432000);       //        64 B
  p.maxcG  = (u32*)   (ws + 2432064);       //        64 B
  p.out    = (float*)d_out;

  void* args[] = { &p };
  hipLaunchCooperativeKernel((void*)k_mega, dim3(128), dim3(1024), args, 0, stream);
}

// Round 4
// 193.325 us; speedup vs baseline: 1.7109x; 1.7109x over previous
//
#include <hip/hip_runtime.h>
#include <stdint.h>

#define NANCH 17064
#define BATCH 16
#define NCLS 80
#define KDET 1000
#define SCORE_THR 0.05f
#define IOU_THR 0.6f

typedef unsigned long long u64;
typedef unsigned int u32;

__device__ __forceinline__ float sigf(float x) { return 1.0f / (1.0f + expf(-x)); }

__device__ __forceinline__ void decode_anchor(int n, int& l, int& h, int& w) {
  if (n < 12800)      { l = 0; h = n >> 7;               w = n & 127; }
  else if (n < 16000) { l = 1; int r = n - 12800; h = r >> 6; w = r & 63; }
  else if (n < 16800) { l = 2; int r = n - 16000; h = r >> 5; w = r & 31; }
  else if (n < 17008) { l = 3; int r = n - 16800; h = r >> 4; w = r & 15; }
  else                { l = 4; int r = n - 17008; h = r >> 3; w = r & 7; }
}

// encode float for monotone u32 atomicMax
__device__ __forceinline__ u32 fenc(float f) {
  u32 u = __float_as_uint(f);
  return (u & 0x80000000u) ? ~u : (u | 0x80000000u);
}
__device__ __forceinline__ float fdec(u32 e) {
  u32 u = (e & 0x80000000u) ? (e ^ 0x80000000u) : ~e;
  return __uint_as_float(u);
}

// ---------------- kernel 1: per-anchor scores ----------------
// Block (64,4): tid.x = quad lane (4 anchors via float4), tid.y = class block
// (20 classes). ALL 20 class loads issued before any sigmoid (ILP=20 covers
// ~900cy HBM latency at 4 waves/SIMD). NOTE round-3 lesson: this needs >=84
// VGPRs; any VGPR cap (e.g. 1024-thread block with low launch_bounds) makes
// the compiler serialize the 20 loads -> 460 GB/s instead of ~6 TB/s.
__global__ __launch_bounds__(256, 4) void k_score(
    const float* __restrict__ cls0, const float* __restrict__ ctr0,
    const float* __restrict__ cls1, const float* __restrict__ ctr1,
    const float* __restrict__ cls2, const float* __restrict__ ctr2,
    const float* __restrict__ cls3, const float* __restrict__ ctr3,
    const float* __restrict__ cls4, const float* __restrict__ ctr4,
    u32* __restrict__ sb, u32* __restrict__ cl8)
{
  __shared__ float sm[4][64][5];   // [yblk][lane][anchor(+pad)]
  __shared__ u32 sa[4][64];        // packed 4×u8 argmax per quad

  const int x = threadIdx.x;       // 0..63
  const int y = threadIdx.y;       // 0..3
  const int b = blockIdx.y;
  int q = blockIdx.x * 64 + x;
  const bool act = (q < NANCH / 4);
  int qc = act ? q : (NANCH / 4 - 1);
  int n = qc * 4;

  const float* cp; const float* tp; int hw, off;
  if (n < 12800)      { cp = cls0; tp = ctr0; hw = 12800; off = n; }
  else if (n < 16000) { cp = cls1; tp = ctr1; hw = 3200;  off = n - 12800; }
  else if (n < 16800) { cp = cls2; tp = ctr2; hw = 800;   off = n - 16000; }
  else if (n < 17008) { cp = cls3; tp = ctr3; hw = 208;   off = n - 16800; }
  else                { cp = cls4; tp = ctr4; hw = 56;    off = n - 17008; }
  const float4* base = (const float4*)(cp + (size_t)b * NCLS * hw + off);
  const int s4 = hw >> 2;
  const int cb = y * 20;

  // issue all 20 loads up-front
  float4 v[20];
#pragma unroll
  for (int cc = 0; cc < 20; ++cc) v[cc] = base[(size_t)(cb + cc) * s4];

  float m0 = -1.0f, m1 = -1.0f, m2 = -1.0f, m3 = -1.0f;
  int a0 = 0, a1 = 0, a2 = 0, a3 = 0;
#pragma unroll
  for (int cc = 0; cc < 20; ++cc) {
    int c = cb + cc;
    float s;
    s = sigf(v[cc].x); if (s > m0) { m0 = s; a0 = c; }
    s = sigf(v[cc].y); if (s > m1) { m1 = s; a1 = c; }
    s = sigf(v[cc].z); if (s > m2) { m2 = s; a2 = c; }
    s = sigf(v[cc].w); if (s > m3) { m3 = s; a3 = c; }
  }
  sm[y][x][0] = m0; sm[y][x][1] = m1; sm[y][x][2] = m2; sm[y][x][3] = m3;
  sa[y][x] = (u32)a0 | ((u32)a1 << 8) | ((u32)a2 << 16) | ((u32)a3 << 24);
  __syncthreads();

  if (y == 0 && act) {
#pragma unroll
    for (int k = 1; k < 4; ++k) {
      u32 pk = sa[k][x];
      float t;
      t = sm[k][x][0]; if (t > m0) { m0 = t; a0 = (int)(pk & 0xffu); }
      t = sm[k][x][1]; if (t > m1) { m1 = t; a1 = (int)((pk >> 8) & 0xffu); }
      t = sm[k][x][2]; if (t > m2) { m2 = t; a2 = (int)((pk >> 16) & 0xffu); }
      t = sm[k][x][3]; if (t > m3) { m3 = t; a3 = (int)((pk >> 24) & 0xffu); }
    }
    float4 ctv = *(const float4*)(tp + (size_t)b * hw + off);
    uint4 sv;
    sv.x = __float_as_uint(m0 * sigf(ctv.x));
    sv.y = __float_as_uint(m1 * sigf(ctv.y));
    sv.z = __float_as_uint(m2 * sigf(ctv.z));
    sv.w = __float_as_uint(m3 * sigf(ctv.w));
    *(uint4*)(sb + b * NANCH + n) = sv;
    cl8[(b * NANCH + n) >> 2] = (u32)a0 | ((u32)a1 << 8) | ((u32)a2 << 16) | ((u32)a3 << 24);
  }
}

// ---------------- kernel 2: radix thresholds + candidate compaction ----------------
// Scores register-cached: ONE global read pass instead of three.
// 8-way bank-interleaved sub-histograms: hot-bin same-address LDS atomic
// serialization drops from <=64-way (one wave, one address) to <=8-way.
__global__ __launch_bounds__(1024) void k_topk(
    const u32* __restrict__ sb,
    u64* __restrict__ candG, int* __restrict__ cntG, u32* __restrict__ maxcG)
{
  __shared__ u32 subhist[8192];    // [bin*8 + copy], 1024 bins x 8 copies = 32 KB
  __shared__ u32 wtot[16];
  __shared__ int s_T1, s_above, s_T2, s_cnt;

  const int tid = threadIdx.x;
  const int b = blockIdx.x;
  const int lane = tid & 63, wv = tid >> 6;
  const int cpy = tid & 7;
  const u32* sbb = sb + b * NANCH;

  // register cache: up to 17 scores/thread
  u32 sc[17];
#pragma unroll
  for (int k = 0; k < 17; ++k) {
    int n = tid + (k << 10);
    sc[k] = (n < NANCH) ? sbb[n] : 0u;
  }

  // ---- Phase 1: coarse histogram bits[31:22] ----
#pragma unroll
  for (int k = 0; k < 8; ++k) subhist[tid + (k << 10)] = 0;
  __syncthreads();
#pragma unroll
  for (int k = 0; k < 17; ++k) {
    int n = tid + (k << 10);
    if (n < NANCH) atomicAdd(&subhist[((sc[k] >> 22) << 3) + cpy], 1u);
  }
  __syncthreads();
  u32 h = 0;
#pragma unroll
  for (int c = 0; c < 8; ++c) h += subhist[(tid << 3) + c];
  __syncthreads();                    // all merge reads done before re-zero
#pragma unroll
  for (int k = 0; k < 8; ++k) subhist[tid + (k << 10)] = 0;   // prep phase 2
  u32 s = h;
  for (int d = 1; d < 64; d <<= 1) { u32 y = (u32)__shfl_down((int)s, d); if (lane + d < 64) s += y; }
  if (lane == 0) wtot[wv] = s;
  __syncthreads();
  {
    u32 add = 0;
    for (int w2 = wv + 1; w2 < 16; ++w2) add += wtot[w2];
    s += add;
  }
  if (s >= (u32)KDET && s - h < (u32)KDET) { s_T1 = tid; s_above = (int)(s - h); }
  __syncthreads();
  const int T1 = s_T1; const int above = s_above;

  // ---- Phase 2: fine histogram bits[21:12] within bin T1 ----
#pragma unroll
  for (int k = 0; k < 17; ++k) {
    int n = tid + (k << 10);
    u32 bits = sc[k];
    if (n < NANCH && (int)(bits >> 22) == T1)
      atomicAdd(&subhist[(((bits >> 12) & 1023u) << 3) + cpy], 1u);
  }
  __syncthreads();
  h = 0;
#pragma unroll
  for (int c = 0; c < 8; ++c) h += subhist[(tid << 3) + c];
  s = h;
  for (int d = 1; d < 64; d <<= 1) { u32 y = (u32)__shfl_down((int)s, d); if (lane + d < 64) s += y; }
  if (lane == 0) wtot[wv] = s;
  __syncthreads();
  {
    u32 add = 0;
    for (int w2 = wv + 1; w2 < 16; ++w2) add += wtot[w2];
    s += add;
  }
  if (above + (int)s >= KDET && above + (int)(s - h) < KDET) s_T2 = tid;
  if (tid == 0) s_cnt = 0;
  __syncthreads();
  const int T2 = s_T2;

  // ---- Phase 3: compact candidates to global (order irrelevant; rank fixes position) ----
#pragma unroll
  for (int k = 0; k < 17; ++k) {
    int n = tid + (k << 10);
    u32 bits = sc[k];
    int c1 = (int)(bits >> 22);
    bool cand = (n < NANCH) &&
                ((c1 > T1) || (c1 == T1 && (int)((bits >> 12) & 1023u) >= T2));
    if (cand) {
      int pos = atomicAdd(&s_cnt, 1);
      if (pos < 2048) candG[b * 2048 + pos] = ((u64)bits << 32) | (u64)(u32)(~(u32)n);
    }
  }
  __syncthreads();
  if (tid == 0) {
    int C = s_cnt; if (C > 2048) C = 2048;
    cntG[b] = C;
    maxcG[b] = 0u;  // encoded -inf floor
  }
}

// ---------------- kernel 3: rank candidates, winners stage box/score/class ----------------
// LDS-staged keys; compare loop is LDS-ISSUE-PIPE bound (waves on a CU share
// one LDS pipe: time = waves/CU * C/2 * ~12cy). So: 128-thread blocks spread
// over 256 blocks -> 2 waves/CU instead of 4 -> compare phase halves.
// Global-uniform-load variant was 44us (latency-serialized, r1) — don't.
__global__ __launch_bounds__(128) void k_rank(
    const float* __restrict__ reg0, const float* __restrict__ reg1,
    const float* __restrict__ reg2, const float* __restrict__ reg3,
    const float* __restrict__ reg4,
    const unsigned char* __restrict__ cl8,
    const u64* __restrict__ candG, const int* __restrict__ cntG,
    float* __restrict__ scoreG, int* __restrict__ clsG, float4* __restrict__ boxG,
    u32* __restrict__ maxcG)
{
  __shared__ ulonglong2 keys2[1024];
  const int tid = threadIdx.x;         // 0..127
  const int c = blockIdx.x;            // 0..15
  const int b = blockIdx.y;
  const int lane = tid & 63;
  const int C = cntG[b];
  if (c * 128 >= C) return;            // whole chunk empty: skip staging+loop
  const u64* cand = candG + b * 2048;

  for (int i = tid; i < 1024; i += 128) {
    int i0 = 2 * i, i1 = 2 * i + 1;
    ulonglong2 v;
    v.x = (i0 < C) ? cand[i0] : 0ull;
    v.y = (i1 < C) ? cand[i1] : 0ull;
    keys2[i] = v;
  }
  __syncthreads();

  const int idx = c * 128 + tid;
  const bool active = (idx < C);
  u64 key = active ? cand[idx] : 0ull;

  int cnt = 0;
  const int Cp2 = ((C + 7) >> 3) << 2;
  for (int s = 0; s < Cp2; s += 4) {
    ulonglong2 a0 = keys2[s], a1 = keys2[s + 1], a2 = keys2[s + 2], a3 = keys2[s + 3];
    cnt += (a0.x > key) + (a0.y > key) + (a1.x > key) + (a1.y > key)
         + (a2.x > key) + (a2.y > key) + (a3.x > key) + (a3.y > key);
  }

  u32 enc = 0u;
  if (active && cnt < KDET) {
    u32 bits = (u32)(key >> 32);
    int n = (int)(~(u32)(key & 0xFFFFFFFFull));
    float score = __uint_as_float(bits);
    int clsv = (int)cl8[b * NANCH + n] + 1;
    int l, hh, ww; decode_anchor(n, l, hh, ww);
    const float* rp; int W, ST, HF, hw;
    switch (l) {
      case 0: rp = reg0; W = 128; ST = 8;   HF = 4;  hw = 12800; break;
      case 1: rp = reg1; W = 64;  ST = 16;  HF = 8;  hw = 3200;  break;
      case 2: rp = reg2; W = 32;  ST = 32;  HF = 16; hw = 800;   break;
      case 3: rp = reg3; W = 16;  ST = 64;  HF = 32; hw = 208;   break;
      default: rp = reg4; W = 8;  ST = 128; HF = 64; hw = 56;    break;
    }
    float cx = (float)(ww * ST + HF);
    float cy = (float)(hh * ST + HF);
    const float* rb = rp + (size_t)b * 4 * hw + hh * W + ww;
    float r0 = rb[0], r1 = rb[hw], r2 = rb[2 * hw], r3 = rb[3 * hw];
    float4 bx = make_float4(cx - r0, cy - r1, cx + r2, cy + r3);
    int o = b * KDET + cnt;
    scoreG[o] = score; clsG[o] = clsv; boxG[o] = bx;
    enc = fenc(fmaxf(fmaxf(bx.x, bx.y), fmaxf(bx.z, bx.w)));
  }
  for (int d = 32; d > 0; d >>= 1) {
    u32 o = (u32)__shfl_xor((int)enc, d);
    enc = (o > enc) ? o : enc;
  }
  if (lane == 0 && enc != 0u) atomicMax(maxcG + b, enc);
}

// ---------------- kernel 4: transposed suppression matrix, register-only tiles ----------------
// matT[i][wc] bit j: (j < i) && iou(i,j) > thr
__global__ __launch_bounds__(256) void k_mat(
    const float4* __restrict__ boxG, const int* __restrict__ clsG,
    const u32* __restrict__ maxcG, u64* __restrict__ mat)
{
  const int tid = threadIdx.x, lane = tid & 63, wv = tid >> 6;
  const int b = blockIdx.y;
  const int tile = blockIdx.x * 4 + wv;
  if (tile >= 136) return;
  int rt = 0, rem = tile;
  while (rem >= rt + 1) { rem -= rt + 1; ++rt; }
  const int wc = rem;

  const float scale = fdec(maxcG[b]) + 1.0f;

  const int j = (wc << 6) + lane;
  float jx1 = 0, jy1 = 0, jx2 = 0, jy2 = 0, aj = 0;
  if (j < KDET) {
    float4 bj = boxG[b * KDET + j];
    float off = (float)clsG[b * KDET + j] * scale;
    jx1 = bj.x + off; jy1 = bj.y + off; jx2 = bj.z + off; jy2 = bj.w + off;
    aj = (jx2 - jx1 + 1.0f) * (jy2 - jy1 + 1.0f);
  }
  const int ri = (rt << 6) + lane;
  float ix1 = 0, iy1 = 0, ix2 = 0, iy2 = 0;
  if (ri < KDET) {
    float4 bi = boxG[b * KDET + ri];
    float off = (float)clsG[b * KDET + ri] * scale;
    ix1 = bi.x + off; iy1 = bi.y + off; ix2 = bi.z + off; iy2 = bi.w + off;
  }

  u64 myword = 0ull;
  for (int r = 0; r < 64; ++r) {
    float x1 = __shfl(ix1, r), y1 = __shfl(iy1, r);
    float x2 = __shfl(ix2, r), y2 = __shfl(iy2, r);
    float ai = (x2 - x1 + 1.0f) * (y2 - y1 + 1.0f);
    int row = (rt << 6) + r;
    float xmin = fmaxf(x1, jx1), ymin = fmaxf(y1, jy1);
    float xmax = fminf(x2, jx2), ymax = fminf(y2, jy2);
    float inter = fmaxf(xmax - xmin, 0.0f) * fmaxf(ymax - ymin, 0.0f);
    float iou = inter / ((ai + aj) - inter);
    bool p = (j < row) && (j < KDET) && (iou > IOU_THR);
    u64 mm = __ballot(p);
    if (lane == r) myword = mm;
  }
  const int rowl = (rt << 6) + lane;
  if (rowl < KDET) mat[(size_t)b * (KDET * 16) + rowl * 16 + wc] = myword;
}

// ---------------- kernel 5: exact greedy NMS via Jacobi fixpoint + outputs ----------------
__global__ __launch_bounds__(1024) void k_nms(
    const u64* __restrict__ mat, const float* __restrict__ scoreG,
    const int* __restrict__ clsG, const float4* __restrict__ boxG,
    float* __restrict__ out)
{
  __shared__ u64 keptS[16];
  __shared__ int s_chg;
  const int tid = threadIdx.x;
  const int b = blockIdx.x;
  const int wv = tid >> 6, lane = tid & 63;

  float sc = (tid < KDET) ? scoreG[b * KDET + tid] : 0.0f;
  bool valid = (tid < KDET) && (sc >= SCORE_THR);

  u64 row[16];
  const u64* mrow = mat + (size_t)b * (KDET * 16) + (size_t)tid * 16;
  const int wtop = tid >> 6;
#pragma unroll
  for (int w = 0; w < 16; ++w)
    row[w] = (tid < KDET && w <= wtop) ? mrow[w] : 0ull;

  {
    u64 mb = __ballot(valid);
    if (lane == 0) keptS[wv] = mb;
  }
  __syncthreads();

  for (int it = 0; it < KDET + 1; ++it) {
    u64 sup = 0;
    // w is compile-time, wtop is wave-uniform: low waves skip dead LDS reads
    // via s_cbranch_execz instead of issuing 16 reads each.
#pragma unroll
    for (int w = 0; w < 16; ++w)
      if (w <= wtop) sup |= keptS[w] & row[w];
    bool nk = valid && (sup == 0ull);
    u64 nw = __ballot(nk);
    if (tid == 0) s_chg = 0;
    __syncthreads();
    if (lane == 0) {
      if (nw != keptS[wv]) s_chg = 1;
      keptS[wv] = nw;
    }
    __syncthreads();
    if (s_chg == 0) break;
  }

  if (tid < KDET) {
    bool kp = ((keptS[tid >> 6] >> (tid & 63)) & 1ull) != 0ull;
    int o1 = b * KDET + tid;
    out[o1] = kp ? sc : 0.0f;
    out[BATCH * KDET + o1] = kp ? (float)clsG[o1] : 0.0f;
    float4 bx = boxG[o1];
    float* ob = out + 2 * BATCH * KDET + (size_t)o1 * 4;
    ob[0] = kp ? bx.x : 0.0f;
    ob[1] = kp ? bx.y : 0.0f;
    ob[2] = kp ? bx.z : 0.0f;
    ob[3] = kp ? bx.w : 0.0f;
  }
}

extern "C" void kernel_launch(void* const* d_in, const int* in_sizes, int n_in,
                              void* d_out, int out_size, void* d_ws, size_t ws_size,
                              hipStream_t stream) {
  const float* cls[5]; const float* ctr[5]; const float* reg[5];
  for (int i = 0; i < 5; ++i) {
    cls[i] = (const float*)d_in[3 * i + 0];
    ctr[i] = (const float*)d_in[3 * i + 1];
    reg[i] = (const float*)d_in[3 * i + 2];
  }
  char* ws = (char*)d_ws;
  // mat region (0 .. 2,048,000) is overlaid by sb/cl8/candG, all dead before k_mat writes.
  u32* sb   = (u32*)ws;                                  // 1,092,096 B
  unsigned char* cl8 = (unsigned char*)(ws + 1092096);   //   273,024 B (dead after k_rank)
  u64* candG = (u64*)(ws + 1365120);                     //   262,144 B (dead after k_rank)
  u64* mat  = (u64*)ws;                                  // 2,048,000 B
  float*  scoreG = (float*) (ws + 2048000);              //    64,000 B
  int*    clsG   = (int*)   (ws + 2112000);              //    64,000 B
  float4* boxG   = (float4*)(ws + 2176000);              //   256,000 B
  int*    cntG   = (int*)   (ws + 2432000);              //        64 B
  u32*    maxcG  = (u32*)   (ws + 2432064);              //        64 B

  dim3 g1((NANCH / 4 + 63) / 64, BATCH);
  k_score<<<g1, dim3(64, 4), 0, stream>>>(cls[0], ctr[0], cls[1], ctr[1], cls[2], ctr[2],
                                          cls[3], ctr[3], cls[4], ctr[4], sb, (u32*)cl8);
  k_topk<<<BATCH, 1024, 0, stream>>>(sb, candG, cntG, maxcG);
  k_rank<<<dim3(16, BATCH), 128, 0, stream>>>(reg[0], reg[1], reg[2], reg[3], reg[4],
                                              cl8, candG, cntG, scoreG, clsG, boxG, maxcG);
  k_mat<<<dim3(34, BATCH), 256, 0, stream>>>(boxG, clsG, maxcG, mat);
  k_nms<<<BATCH, 1024, 0, stream>>>(mat, scoreG, clsG, boxG, (float*)d_out);
}

// Round 6
// 192.422 us; speedup vs baseline: 1.7190x; 1.0047x over previous
//
#include <hip/hip_runtime.h>
#include <stdint.h>

#define NANCH 17064
#define BATCH 16
#define NCLS 80
#define KDET 1000
#define SCORE_THR 0.05f
#define IOU_THR 0.6f

typedef unsigned long long u64;
typedef unsigned int u32;

__device__ __forceinline__ float sigf(float x) { return 1.0f / (1.0f + expf(-x)); }

__device__ __forceinline__ void decode_anchor(int n, int& l, int& h, int& w) {
  if (n < 12800)      { l = 0; h = n >> 7;               w = n & 127; }
  else if (n < 16000) { l = 1; int r = n - 12800; h = r >> 6; w = r & 63; }
  else if (n < 16800) { l = 2; int r = n - 16000; h = r >> 5; w = r & 31; }
  else if (n < 17008) { l = 3; int r = n - 16800; h = r >> 4; w = r & 15; }
  else                { l = 4; int r = n - 17008; h = r >> 3; w = r & 7; }
}

// encode float for monotone u32 atomicMax
__device__ __forceinline__ u32 fenc(float f) {
  u32 u = __float_as_uint(f);
  return (u & 0x80000000u) ? ~u : (u | 0x80000000u);
}
__device__ __forceinline__ float fdec(u32 e) {
  u32 u = (e & 0x80000000u) ? (e ^ 0x80000000u) : ~e;
  return __uint_as_float(u);
}

// ---------------- kernel 1: per-anchor scores ----------------
// Block (64,4): tid.x = quad lane (4 anchors via float4), tid.y = class block
// (20 classes). Round-4 postmortem: WITHOUT a scheduling fence the compiler
// re-interleaves loads with sigmoid compute to fit 60 VGPRs (ILP~2, 843 GB/s,
// 54us). sched_barrier(0) after the load batch forces all 21 loads issued
// back-to-back (~100 VGPR, legal under the 128 cap of launch_bounds(256,4));
// grid limits occupancy to ~4 blocks/CU anyway, so the VGPR rise is free.
__global__ __launch_bounds__(256, 4) void k_score(
    const float* __restrict__ cls0, const float* __restrict__ ctr0,
    const float* __restrict__ cls1, const float* __restrict__ ctr1,
    const float* __restrict__ cls2, const float* __restrict__ ctr2,
    const float* __restrict__ cls3, const float* __restrict__ ctr3,
    const float* __restrict__ cls4, const float* __restrict__ ctr4,
    u32* __restrict__ sb, u32* __restrict__ cl8)
{
  __shared__ float sm[4][64][5];   // [yblk][lane][anchor(+pad)]
  __shared__ u32 sa[4][64];        // packed 4×u8 argmax per quad

  const int x = threadIdx.x;       // 0..63
  const int y = threadIdx.y;       // 0..3
  const int b = blockIdx.y;
  int q = blockIdx.x * 64 + x;
  const bool act = (q < NANCH / 4);
  int qc = act ? q : (NANCH / 4 - 1);
  int n = qc * 4;

  const float* cp; const float* tp; int hw, off;
  if (n < 12800)      { cp = cls0; tp = ctr0; hw = 12800; off = n; }
  else if (n < 16000) { cp = cls1; tp = ctr1; hw = 3200;  off = n - 12800; }
  else if (n < 16800) { cp = cls2; tp = ctr2; hw = 800;   off = n - 16000; }
  else if (n < 17008) { cp = cls3; tp = ctr3; hw = 208;   off = n - 16800; }
  else                { cp = cls4; tp = ctr4; hw = 56;    off = n - 17008; }
  const float4* base = (const float4*)(cp + (size_t)b * NCLS * hw + off);
  const int s4 = hw >> 2;
  const int cb = y * 20;

  // issue all 20 class loads + (y==0) ctr load up-front, then FENCE so the
  // scheduler cannot sink them into the compute loop.
  float4 v[20];
#pragma unroll
  for (int cc = 0; cc < 20; ++cc) v[cc] = base[(size_t)(cb + cc) * s4];
  float4 ctv = make_float4(0.f, 0.f, 0.f, 0.f);
  if (y == 0) ctv = *(const float4*)(tp + (size_t)b * hw + off);
  __builtin_amdgcn_sched_barrier(0);

  float m0 = -1.0f, m1 = -1.0f, m2 = -1.0f, m3 = -1.0f;
  int a0 = 0, a1 = 0, a2 = 0, a3 = 0;
#pragma unroll
  for (int cc = 0; cc < 20; ++cc) {
    int c = cb + cc;
    float s;
    s = sigf(v[cc].x); if (s > m0) { m0 = s; a0 = c; }
    s = sigf(v[cc].y); if (s > m1) { m1 = s; a1 = c; }
    s = sigf(v[cc].z); if (s > m2) { m2 = s; a2 = c; }
    s = sigf(v[cc].w); if (s > m3) { m3 = s; a3 = c; }
  }
  sm[y][x][0] = m0; sm[y][x][1] = m1; sm[y][x][2] = m2; sm[y][x][3] = m3;
  sa[y][x] = (u32)a0 | ((u32)a1 << 8) | ((u32)a2 << 16) | ((u32)a3 << 24);
  __syncthreads();

  if (y == 0 && act) {
#pragma unroll
    for (int k = 1; k < 4; ++k) {
      u32 pk = sa[k][x];
      float t;
      t = sm[k][x][0]; if (t > m0) { m0 = t; a0 = (int)(pk & 0xffu); }
      t = sm[k][x][1]; if (t > m1) { m1 = t; a1 = (int)((pk >> 8) & 0xffu); }
      t = sm[k][x][2]; if (t > m2) { m2 = t; a2 = (int)((pk >> 16) & 0xffu); }
      t = sm[k][x][3]; if (t > m3) { m3 = t; a3 = (int)((pk >> 24) & 0xffu); }
    }
    uint4 sv;
    sv.x = __float_as_uint(m0 * sigf(ctv.x));
    sv.y = __float_as_uint(m1 * sigf(ctv.y));
    sv.z = __float_as_uint(m2 * sigf(ctv.z));
    sv.w = __float_as_uint(m3 * sigf(ctv.w));
    *(uint4*)(sb + b * NANCH + n) = sv;
    cl8[(b * NANCH + n) >> 2] = (u32)a0 | ((u32)a1 << 8) | ((u32)a2 << 16) | ((u32)a3 << 24);
  }
}

// ---------------- kernel 2: radix thresholds + candidate compaction ----------------
// Scores register-cached: ONE global read pass instead of three.
// 8-way bank-interleaved sub-histograms: hot-bin same-address LDS atomic
// serialization drops from <=64-way (one wave, one address) to <=8-way.
__global__ __launch_bounds__(1024) void k_topk(
    const u32* __restrict__ sb,
    u64* __restrict__ candG, int* __restrict__ cntG, u32* __restrict__ maxcG)
{
  __shared__ u32 subhist[8192];    // [bin*8 + copy], 1024 bins x 8 copies = 32 KB
  __shared__ u32 wtot[16];
  __shared__ int s_T1, s_above, s_T2, s_cnt;

  const int tid = threadIdx.x;
  const int b = blockIdx.x;
  const int lane = tid & 63, wv = tid >> 6;
  const int cpy = tid & 7;
  const u32* sbb = sb + b * NANCH;

  // register cache: up to 17 scores/thread
  u32 sc[17];
#pragma unroll
  for (int k = 0; k < 17; ++k) {
    int n = tid + (k << 10);
    sc[k] = (n < NANCH) ? sbb[n] : 0u;
  }

  // ---- Phase 1: coarse histogram bits[31:22] ----
#pragma unroll
  for (int k = 0; k < 8; ++k) subhist[tid + (k << 10)] = 0;
  __syncthreads();
#pragma unroll
  for (int k = 0; k < 17; ++k) {
    int n = tid + (k << 10);
    if (n < NANCH) atomicAdd(&subhist[((sc[k] >> 22) << 3) + cpy], 1u);
  }
  __syncthreads();
  u32 h = 0;
#pragma unroll
  for (int c = 0; c < 8; ++c) h += subhist[(tid << 3) + c];
  __syncthreads();                    // all merge reads done before re-zero
#pragma unroll
  for (int k = 0; k < 8; ++k) subhist[tid + (k << 10)] = 0;   // prep phase 2
  u32 s = h;
  for (int d = 1; d < 64; d <<= 1) { u32 y = (u32)__shfl_down((int)s, d); if (lane + d < 64) s += y; }
  if (lane == 0) wtot[wv] = s;
  __syncthreads();
  {
    u32 add = 0;
    for (int w2 = wv + 1; w2 < 16; ++w2) add += wtot[w2];
    s += add;
  }
  if (s >= (u32)KDET && s - h < (u32)KDET) { s_T1 = tid; s_above = (int)(s - h); }
  __syncthreads();
  const int T1 = s_T1; const int above = s_above;

  // ---- Phase 2: fine histogram bits[21:12] within bin T1 ----
#pragma unroll
  for (int k = 0; k < 17; ++k) {
    int n = tid + (k << 10);
    u32 bits = sc[k];
    if (n < NANCH && (int)(bits >> 22) == T1)
      atomicAdd(&subhist[(((bits >> 12) & 1023u) << 3) + cpy], 1u);
  }
  __syncthreads();
  h = 0;
#pragma unroll
  for (int c = 0; c < 8; ++c) h += subhist[(tid << 3) + c];
  s = h;
  for (int d = 1; d < 64; d <<= 1) { u32 y = (u32)__shfl_down((int)s, d); if (lane + d < 64) s += y; }
  if (lane == 0) wtot[wv] = s;
  __syncthreads();
  {
    u32 add = 0;
    for (int w2 = wv + 1; w2 < 16; ++w2) add += wtot[w2];
    s += add;
  }
  if (above + (int)s >= KDET && above + (int)(s - h) < KDET) s_T2 = tid;
  if (tid == 0) s_cnt = 0;
  __syncthreads();
  const int T2 = s_T2;

  // ---- Phase 3: compact candidates to global (order irrelevant; rank fixes position) ----
#pragma unroll
  for (int k = 0; k < 17; ++k) {
    int n = tid + (k << 10);
    u32 bits = sc[k];
    int c1 = (int)(bits >> 22);
    bool cand = (n < NANCH) &&
                ((c1 > T1) || (c1 == T1 && (int)((bits >> 12) & 1023u) >= T2));
    if (cand) {
      int pos = atomicAdd(&s_cnt, 1);
      if (pos < 2048) candG[b * 2048 + pos] = ((u64)bits << 32) | (u64)(u32)(~(u32)n);
    }
  }
  __syncthreads();
  if (tid == 0) {
    int C = s_cnt; if (C > 2048) C = 2048;
    cntG[b] = C;
    maxcG[b] = 0u;  // encoded -inf floor
  }
}

// ---------------- kernel 3: rank candidates, winners stage box/score/class ----------------
// LDS-staged keys; compare loop is LDS-issue-pipe bound, so 128-thread blocks
// over 256 blocks (2 waves/CU). Global-uniform-load variant was 44us
// (latency-serialized, r1) — don't.
__global__ __launch_bounds__(128) void k_rank(
    const float* __restrict__ reg0, const float* __restrict__ reg1,
    const float* __restrict__ reg2, const float* __restrict__ reg3,
    const float* __restrict__ reg4,
    const unsigned char* __restrict__ cl8,
    const u64* __restrict__ candG, const int* __restrict__ cntG,
    float* __restrict__ scoreG, int* __restrict__ clsG, float4* __restrict__ boxG,
    u32* __restrict__ maxcG)
{
  __shared__ ulonglong2 keys2[1024];
  const int tid = threadIdx.x;         // 0..127
  const int c = blockIdx.x;            // 0..15
  const int b = blockIdx.y;
  const int lane = tid & 63;
  const int C = cntG[b];
  if (c * 128 >= C) return;            // whole chunk empty: skip staging+loop
  const u64* cand = candG + b * 2048;

  for (int i = tid; i < 1024; i += 128) {
    int i0 = 2 * i, i1 = 2 * i + 1;
    ulonglong2 v;
    v.x = (i0 < C) ? cand[i0] : 0ull;
    v.y = (i1 < C) ? cand[i1] : 0ull;
    keys2[i] = v;
  }
  __syncthreads();

  const int idx = c * 128 + tid;
  const bool active = (idx < C);
  u64 key = active ? cand[idx] : 0ull;

  int cnt = 0;
  const int Cp2 = ((C + 7) >> 3) << 2;
  for (int s = 0; s < Cp2; s += 4) {
    ulonglong2 a0 = keys2[s], a1 = keys2[s + 1], a2 = keys2[s + 2], a3 = keys2[s + 3];
    cnt += (a0.x > key) + (a0.y > key) + (a1.x > key) + (a1.y > key)
         + (a2.x > key) + (a2.y > key) + (a3.x > key) + (a3.y > key);
  }

  u32 enc = 0u;
  if (active && cnt < KDET) {
    u32 bits = (u32)(key >> 32);
    int n = (int)(~(u32)(key & 0xFFFFFFFFull));
    float score = __uint_as_float(bits);
    int clsv = (int)cl8[b * NANCH + n] + 1;
    int l, hh, ww; decode_anchor(n, l, hh, ww);
    const float* rp; int W, ST, HF, hw;
    switch (l) {
      case 0: rp = reg0; W = 128; ST = 8;   HF = 4;  hw = 12800; break;
      case 1: rp = reg1; W = 64;  ST = 16;  HF = 8;  hw = 3200;  break;
      case 2: rp = reg2; W = 32;  ST = 32;  HF = 16; hw = 800;   break;
      case 3: rp = reg3; W = 16;  ST = 64;  HF = 32; hw = 208;   break;
      default: rp = reg4; W = 8;  ST = 128; HF = 64; hw = 56;    break;
    }
    float cx = (float)(ww * ST + HF);
    float cy = (float)(hh * ST + HF);
    const float* rb = rp + (size_t)b * 4 * hw + hh * W + ww;
    float r0 = rb[0], r1 = rb[hw], r2 = rb[2 * hw], r3 = rb[3 * hw];
    float4 bx = make_float4(cx - r0, cy - r1, cx + r2, cy + r3);
    int o = b * KDET + cnt;
    scoreG[o] = score; clsG[o] = clsv; boxG[o] = bx;
    enc = fenc(fmaxf(fmaxf(bx.x, bx.y), fmaxf(bx.z, bx.w)));
  }
  for (int d = 32; d > 0; d >>= 1) {
    u32 o = (u32)__shfl_xor((int)enc, d);
    enc = (o > enc) ? o : enc;
  }
  if (lane == 0 && enc != 0u) atomicMax(maxcG + b, enc);
}

// ---------------- kernel 4: transposed suppression matrix, register-only tiles ----------------
// matT[i][wc] bit j: (j < i) && iou(i,j) > thr
__global__ __launch_bounds__(256) void k_mat(
    const float4* __restrict__ boxG, const int* __restrict__ clsG,
    const u32* __restrict__ maxcG, u64* __restrict__ mat)
{
  const int tid = threadIdx.x, lane = tid & 63, wv = tid >> 6;
  const int b = blockIdx.y;
  const int tile = blockIdx.x * 4 + wv;
  if (tile >= 136) return;
  int rt = 0, rem = tile;
  while (rem >= rt + 1) { rem -= rt + 1; ++rt; }
  const int wc = rem;

  const float scale = fdec(maxcG[b]) + 1.0f;

  const int j = (wc << 6) + lane;
  float jx1 = 0, jy1 = 0, jx2 = 0, jy2 = 0, aj = 0;
  if (j < KDET) {
    float4 bj = boxG[b * KDET + j];
    float off = (float)clsG[b * KDET + j] * scale;
    jx1 = bj.x + off; jy1 = bj.y + off; jx2 = bj.z + off; jy2 = bj.w + off;
    aj = (jx2 - jx1 + 1.0f) * (jy2 - jy1 + 1.0f);
  }
  const int ri = (rt << 6) + lane;
  float ix1 = 0, iy1 = 0, ix2 = 0, iy2 = 0;
  if (ri < KDET) {
    float4 bi = boxG[b * KDET + ri];
    float off = (float)clsG[b * KDET + ri] * scale;
    ix1 = bi.x + off; iy1 = bi.y + off; ix2 = bi.z + off; iy2 = bi.w + off;
  }

  u64 myword = 0ull;
  for (int r = 0; r < 64; ++r) {
    float x1 = __shfl(ix1, r), y1 = __shfl(iy1, r);
    float x2 = __shfl(ix2, r), y2 = __shfl(iy2, r);
    float ai = (x2 - x1 + 1.0f) * (y2 - y1 + 1.0f);
    int row = (rt << 6) + r;
    float xmin = fmaxf(x1, jx1), ymin = fmaxf(y1, jy1);
    float xmax = fminf(x2, jx2), ymax = fminf(y2, jy2);
    float inter = fmaxf(xmax - xmin, 0.0f) * fmaxf(ymax - ymin, 0.0f);
    float iou = inter / ((ai + aj) - inter);
    bool p = (j < row) && (j < KDET) && (iou > IOU_THR);
    u64 mm = __ballot(p);
    if (lane == r) myword = mm;
  }
  const int rowl = (rt << 6) + lane;
  if (rowl < KDET) mat[(size_t)b * (KDET * 16) + rowl * 16 + wc] = myword;
}

// ---------------- kernel 5: exact greedy NMS via Jacobi fixpoint + outputs ----------------
__global__ __launch_bounds__(1024) void k_nms(
    const u64* __restrict__ mat, const float* __restrict__ scoreG,
    const int* __restrict__ clsG, const float4* __restrict__ boxG,
    float* __restrict__ out)
{
  __shared__ u64 keptS[16];
  __shared__ int s_chg;
  const int tid = threadIdx.x;
  const int b = blockIdx.x;
  const int wv = tid >> 6, lane = tid & 63;

  float sc = (tid < KDET) ? scoreG[b * KDET + tid] : 0.0f;
  bool valid = (tid < KDET) && (sc >= SCORE_THR);

  u64 row[16];
  const u64* mrow = mat + (size_t)b * (KDET * 16) + (size_t)tid * 16;
  const int wtop = tid >> 6;
#pragma unroll
  for (int w = 0; w < 16; ++w)
    row[w] = (tid < KDET && w <= wtop) ? mrow[w] : 0ull;

  {
    u64 mb = __ballot(valid);
    if (lane == 0) keptS[wv] = mb;
  }
  __syncthreads();

  for (int it = 0; it < KDET + 1; ++it) {
    u64 sup = 0;
    // w is compile-time, wtop is wave-uniform: low waves skip dead LDS reads
    // via s_cbranch_execz instead of issuing 16 reads each.
#pragma unroll
    for (int w = 0; w < 16; ++w)
      if (w <= wtop) sup |= keptS[w] & row[w];
    bool nk = valid && (sup == 0ull);
    u64 nw = __ballot(nk);
    if (tid == 0) s_chg = 0;
    __syncthreads();
    if (lane == 0) {
      if (nw != keptS[wv]) s_chg = 1;
      keptS[wv] = nw;
    }
    __syncthreads();
    if (s_chg == 0) break;
  }

  if (tid < KDET) {
    bool kp = ((keptS[tid >> 6] >> (tid & 63)) & 1ull) != 0ull;
    int o1 = b * KDET + tid;
    out[o1] = kp ? sc : 0.0f;
    out[BATCH * KDET + o1] = kp ? (float)clsG[o1] : 0.0f;
    float4 bx = boxG[o1];
    float* ob = out + 2 * BATCH * KDET + (size_t)o1 * 4;
    ob[0] = kp ? bx.x : 0.0f;
    ob[1] = kp ? bx.y : 0.0f;
    ob[2] = kp ? bx.z : 0.0f;
    ob[3] = kp ? bx.w : 0.0f;
  }
}

extern "C" void kernel_launch(void* const* d_in, const int* in_sizes, int n_in,
                              void* d_out, int out_size, void* d_ws, size_t ws_size,
                              hipStream_t stream) {
  const float* cls[5]; const float* ctr[5]; const float* reg[5];
  for (int i = 0; i < 5; ++i) {
    cls[i] = (const float*)d_in[3 * i + 0];
    ctr[i] = (const float*)d_in[3 * i + 1];
    reg[i] = (const float*)d_in[3 * i + 2];
  }
  char* ws = (char*)d_ws;
  // mat region (0 .. 2,048,000) is overlaid by sb/cl8/candG, all dead before k_mat writes.
  u32* sb   = (u32*)ws;                                  // 1,092,096 B
  unsigned char* cl8 = (unsigned char*)(ws + 1092096);   //   273,024 B (dead after k_rank)
  u64* candG = (u64*)(ws + 1365120);                     //   262,144 B (dead after k_rank)
  u64* mat  = (u64*)ws;                                  // 2,048,000 B
  float*  scoreG = (float*) (ws + 2048000);              //    64,000 B
  int*    clsG   = (int*)   (ws + 2112000);              //    64,000 B
  float4* boxG   = (float4*)(ws + 2176000);              //   256,000 B
  int*    cntG   = (int*)   (ws + 2432000);              //        64 B
  u32*    maxcG  = (u32*)   (ws + 2432064);              //        64 B

  dim3 g1((NANCH / 4 + 63) / 64, BATCH);
  k_score<<<g1, dim3(64, 4), 0, stream>>>(cls[0], ctr[0], cls[1], ctr[1], cls[2], ctr[2],
                                          cls[3], ctr[3], cls[4], ctr[4], sb, (u32*)cl8);
  k_topk<<<BATCH, 1024, 0, stream>>>(sb, candG, cntG, maxcG);
  k_rank<<<dim3(16, BATCH), 128, 0, stream>>>(reg[0], reg[1], reg[2], reg[3], reg[4],
                                              cl8, candG, cntG, scoreG, clsG, boxG, maxcG);
  k_mat<<<dim3(34, BATCH), 256, 0, stream>>>(boxG, clsG, maxcG, mat);
  k_nms<<<BATCH, 1024, 0, stream>>>(mat, scoreG, clsG, boxG, (float*)d_out);
}